// Round 12
// baseline (56.574 us; speedup 1.0000x reference)
//
#include <hip/hip_runtime.h>
#include <math.h>

// SSIM 1D loss: B=16, C=32, T=48000, window=11, sigma=1.5, zero padding.
// u/v reformulation: 4 convs (u, v, u^2, v^2) recover all SSIM moments.
//
// R12 = R9 + inline-asm v_pk_fma_f32 conv loop (single-variable change).
// Evidence: VALU-busy ~27us (invariant across R9/R11 replays) == ~680 scalar
// VALU slots/thread == the f32x2 source SCALARIZED. gfx950 has packed-FP32
// VOP3P (v_pk_fma_f32, 2 FMA/lane/issue); hipcc doesn't select it from
// <2 x float> here, so emit it explicitly. 192 pk-FMA replace ~384 scalar.
// launch_bounds(256,4): 128-VGPR cap (occupancy proven irrelevant R9/R11).
constexpr int T     = 48000;
constexpr int TPB   = 256;
constexpr int OPT   = 8;            // outputs per thread
constexpr int TPROW = T / OPT;      // 6000 threads per row (exact)
constexpr float C1f = 0.0001f;      // 0.01^2
constexpr float C2f = 0.0009f;      // 0.03^2

typedef float f32x2 __attribute__((ext_vector_type(2)));
typedef float f32x4 __attribute__((ext_vector_type(4)));

struct WP { f32x2 wp[12]; };        // wp[j] = {g[j], g[j-1]}, 0 outside [0,10]

// acc = s2 * w2 + acc, packed (VOP3P). All operands VGPR pairs.
#define PK_FMA(acc, s2, w2) \
    asm("v_pk_fma_f32 %0, %1, %2, %0" : "+v"(acc) : "v"(s2), "v"(w2))

__global__ __launch_bounds__(TPB, 4) void ssim_main(
    const float* __restrict__ pred, const float* __restrict__ targ,
    float* __restrict__ partial, WP wts)
{
    const int tid  = blockIdx.x * TPB + (int)threadIdx.x;   // grid exact
    const int lane = threadIdx.x & 63;
    const int rp   = (tid % TPROW) * OPT;                   // pos within row
    const size_t base = (size_t)tid * OPT;                  // flat first output

    // ---- own data: exactly x[base .. base+7], unit-stride coalesced ----
    const f32x4* P4 = reinterpret_cast<const f32x4*>(pred + base);
    const f32x4* Q4 = reinterpret_cast<const f32x4*>(targ + base);
    const f32x4 p0 = P4[0], p1 = P4[1];
    const f32x4 q0 = Q4[0], q1 = Q4[1];
    const f32x4 u0 = p0 + q0, u1 = p1 + q1;
    const f32x4 v0 = p0 - q0, v1 = p1 - q1;

    // window index w=0..17 <-> x[base-5+w]; own j=0..7 at w=5+j
    float U[18], V[18];
    U[5]=u0.x; U[6]=u0.y; U[7]=u0.z; U[8]=u0.w; U[9]=u1.x; U[10]=u1.y; U[11]=u1.z; U[12]=u1.w;
    V[5]=v0.x; V[6]=v0.y; V[7]=v0.z; V[8]=v0.w; V[9]=v1.x; V[10]=v1.y; V[11]=v1.z; V[12]=v1.w;

    // ---- halo via shuffles (all lanes active here) ----
    #pragma unroll
    for (int j = 0; j < 5; j++) {                 // left: prev thread's w=8+j
        U[j] = __shfl_up(U[8 + j], 1);
        V[j] = __shfl_up(V[8 + j], 1);
    }
    #pragma unroll
    for (int j = 0; j < 5; j++) {                 // right: next thread's w=5+j
        U[13 + j] = __shfl_down(U[5 + j], 1);
        V[13 + j] = __shfl_down(V[5 + j], 1);
    }

    const bool leftEdge  = (rp == 0);
    const bool rightEdge = (rp == T - OPT);

    // wave-edge lanes: shuffle source invalid -> patch from global
    if (lane == 0 && !leftEdge) {                 // x[base-8 .. base-1], use [3..7]
        const f32x4 a0 = reinterpret_cast<const f32x4*>(pred + base - 8)[0];
        const f32x4 a1 = reinterpret_cast<const f32x4*>(pred + base - 8)[1];
        const f32x4 b0 = reinterpret_cast<const f32x4*>(targ + base - 8)[0];
        const f32x4 b1 = reinterpret_cast<const f32x4*>(targ + base - 8)[1];
        U[0]=a0.w+b0.w; V[0]=a0.w-b0.w;
        U[1]=a1.x+b1.x; V[1]=a1.x-b1.x;
        U[2]=a1.y+b1.y; V[2]=a1.y-b1.y;
        U[3]=a1.z+b1.z; V[3]=a1.z-b1.z;
        U[4]=a1.w+b1.w; V[4]=a1.w-b1.w;
    }
    if (lane == 63 && !rightEdge) {               // x[base+8 .. base+15], use [0..4]
        const f32x4 c0 = reinterpret_cast<const f32x4*>(pred + base + 8)[0];
        const f32x4 c1 = reinterpret_cast<const f32x4*>(pred + base + 8)[1];
        const f32x4 d0 = reinterpret_cast<const f32x4*>(targ + base + 8)[0];
        const f32x4 d1 = reinterpret_cast<const f32x4*>(targ + base + 8)[1];
        U[13]=c0.x+d0.x; V[13]=c0.x-d0.x;
        U[14]=c0.y+d0.y; V[14]=c0.y-d0.y;
        U[15]=c0.z+d0.z; V[15]=c0.z-d0.z;
        U[16]=c0.w+d0.w; V[16]=c0.w-d0.w;
        U[17]=c1.x+d1.x; V[17]=c1.x-d1.x;
    }
    if (leftEdge) {                               // zero pad (row start)
        #pragma unroll
        for (int j = 0; j < 5; j++) { U[j] = 0.f; V[j] = 0.f; }
    }
    if (rightEdge) {                              // zero pad (row end)
        #pragma unroll
        for (int j = 13; j < 18; j++) { U[j] = 0.f; V[j] = 0.f; }
    }

    // ---- consume: window w contributes weight g[w-m] to output m ----
    // output pair (2p,2p+1): j = w-2p, weights wp[j] = {g[j], g[j-1]}, j in [0,11]
    f32x2 cA[4] = {}, cB[4] = {}, cC[4] = {}, cD[4] = {};
    #pragma unroll
    for (int w = 0; w < 18; w++) {
        const float u  = U[w], v = V[w];
        const float uu = u * u, vv = v * v;
        const f32x2 su  = {u,  u },  sv  = {v,  v };
        const f32x2 suu = {uu, uu},  svv = {vv, vv};
        #pragma unroll
        for (int p = 0; p < 4; p++) {
            const int j = w - 2 * p;
            if (j < 0 || j > 11) continue;
            const f32x2 wp = wts.wp[j];           // hoisted to VGPR pair once per j
            PK_FMA(cA[p], su,  wp);               // 192 v_pk_fma_f32 total
            PK_FMA(cB[p], sv,  wp);
            PK_FMA(cC[p], suu, wp);
            PK_FMA(cD[p], svv, wp);
        }
    }

    // ---- packed SSIM epilogue ----
    float qsum = 0.f;
    #pragma unroll
    for (int p = 0; p < 4; p++) {
        const f32x2 aa = cA[p] * cA[p], bb = cB[p] * cB[p];
        const f32x2 e   = 0.5f * (aa - bb);       // 2*mu1*mu2
        const f32x2 f2  = 0.5f * (aa + bb);       // mu1^2+mu2^2
        const f32x2 t2  = 0.5f * (cC[p] - cD[p]); // 2*s12
        const f32x2 sP  = 0.5f * (cC[p] + cD[p]); // s11+s22
        const f32x2 num = (e + C1f) * (t2 - e + C2f);
        const f32x2 den = (f2 + C1f) * (sP - f2 + C2f);
        qsum += num.x * __builtin_amdgcn_rcpf(den.x);   // den >= C1*C2 > 0
        qsum += num.y * __builtin_amdgcn_rcpf(den.y);
    }

    // ---- block reduction -> one partial per block ----
    #pragma unroll
    for (int off = 32; off; off >>= 1) qsum += __shfl_down(qsum, off);
    __shared__ float wsum[TPB / 64];
    if ((threadIdx.x & 63) == 0) wsum[threadIdx.x >> 6] = qsum;
    __syncthreads();
    if (threadIdx.x == 0) {
        float s = 0.f;
        #pragma unroll
        for (int i = 0; i < TPB / 64; i++) s += wsum[i];
        partial[blockIdx.x] = s;
    }
}

__global__ __launch_bounds__(256) void ssim_reduce(
    const f32x4* __restrict__ partial4, int n4, float* __restrict__ out, float inv_n)
{
    float s = 0.f;
    for (int i = threadIdx.x; i < n4; i += 256) {
        const f32x4 p = partial4[i];
        s += (p.x + p.y) + (p.z + p.w);
    }
    #pragma unroll
    for (int off = 32; off; off >>= 1) s += __shfl_down(s, off);
    __shared__ float ws[4];
    if ((threadIdx.x & 63) == 0) ws[threadIdx.x >> 6] = s;
    __syncthreads();
    if (threadIdx.x == 0) {
        float t = 0.f;
        #pragma unroll
        for (int i = 0; i < 4; i++) t += ws[i];
        out[0] = 1.f - t * inv_n;                 // mean(1-ssim) = 1 - mean(ssim)
    }
}

extern "C" void kernel_launch(void* const* d_in, const int* in_sizes, int n_in,
                              void* d_out, int out_size, void* d_ws, size_t ws_size,
                              hipStream_t stream)
{
    const float* pred = (const float*)d_in[0];
    const float* targ = (const float*)d_in[1];
    float* out = (float*)d_out;
    float* partial = (float*)d_ws;

    const int n      = in_sizes[0];               // B*C*T = 24,576,000
    const int blocks = n / OPT / TPB;             // 12,000 exactly (48 KB d_ws)

    // Gaussian window on host in double (matches numpy), then adjacent pairs.
    double g[11], s = 0.0;
    for (int i = 0; i < 11; i++) { g[i] = exp(-((i - 5) * (i - 5)) / 4.5); s += g[i]; }
    float gw[11];
    for (int i = 0; i < 11; i++) gw[i] = (float)(g[i] / s);
    WP wts;
    for (int j = 0; j < 12; j++) {
        wts.wp[j].x = (j <= 10) ? gw[j] : 0.f;
        wts.wp[j].y = (j >= 1) ? gw[j - 1] : 0.f;
    }

    hipLaunchKernelGGL(ssim_main, dim3(blocks), dim3(TPB), 0, stream,
                       pred, targ, partial, wts);
    hipLaunchKernelGGL(ssim_reduce, dim3(1), dim3(256), 0, stream,
                       (const f32x4*)partial, blocks / 4, out, 1.0f / (float)n);
}

// Round 13
// 52.584 us; speedup vs baseline: 1.0759x; 1.0759x over previous
//
#include <hip/hip_runtime.h>
#include <math.h>

// SSIM 1D loss: B=16, C=32, T=48000, window=11, sigma=1.5, zero padding.
// u/v reformulation: 4 convs (u, v, u^2, v^2) recover all SSIM moments.
//
// R13 = R9 + element-axis packed conv (v_pk_fma_f32 with FREE pair operands).
// R12's output-axis packing needed {u,u} splats (144 v_movs) -> regressed.
// Packing adjacent outputs (2p,2p+1) per tap k instead needs data pair
// {x[e], x[e+1]} (consecutive elements, SAME weight g[k] both halves):
//  - even-e pairs = natural register pairs from the loaded quads (free)
//  - odd-e pairs  = one 9-entry offset array (2 movs each, built once)
//  - weights = host-precomputed {g[k],g[k]} splat pairs (zero device cost)
//  - squares via v_pk_mul_f32; accumulators are {conv_2p, conv_2p+1} directly.
// ~176 pk_fma + 38 pk_mul + 36 movs replace ~352 FMA + 76 mul: ~35% fewer
// VALU issues (the dominant measured consumer: ~27us busy of ~44us main).
constexpr int T     = 48000;
constexpr int TPB   = 256;
constexpr int OPT   = 8;            // outputs per thread
constexpr int TPROW = T / OPT;      // 6000 threads per row (exact)
constexpr float C1f = 0.0001f;      // 0.01^2
constexpr float C2f = 0.0009f;      // 0.03^2

typedef float f32x2 __attribute__((ext_vector_type(2)));
typedef float f32x4 __attribute__((ext_vector_type(4)));

struct WS { f32x2 w[11]; };         // w[k] = {g[k], g[k]} splat pairs

// acc(.lo,.hi) += data(.lo,.hi) * wt(.lo,.hi)   (VOP3P, IEEE fma per half)
#define PK_FMA(acc, d, wt) \
    asm("v_pk_fma_f32 %0, %1, %2, %0" : "+v"(acc) : "v"(d), "v"(wt))
// dst = a*a packed
#define PK_SQ(dst, a) \
    asm("v_pk_mul_f32 %0, %1, %1" : "=v"(dst) : "v"(a))

__global__ __launch_bounds__(TPB, 4) void ssim_main(
    const float* __restrict__ pred, const float* __restrict__ targ,
    float* __restrict__ partial, WS wts)
{
    const int tid  = blockIdx.x * TPB + (int)threadIdx.x;   // grid exact
    const int lane = threadIdx.x & 63;
    const int rp   = (tid % TPROW) * OPT;                   // pos within row
    const size_t base = (size_t)tid * OPT;                  // flat first output

    // ---- own data: exactly x[base .. base+7], unit-stride coalesced ----
    const f32x4* P4 = reinterpret_cast<const f32x4*>(pred + base);
    const f32x4* Q4 = reinterpret_cast<const f32x4*>(targ + base);
    const f32x4 p0 = P4[0], p1 = P4[1];
    const f32x4 q0 = Q4[0], q1 = Q4[1];
    const f32x4 u0 = p0 + q0, u1 = p1 + q1;
    const f32x4 v0 = p0 - q0, v1 = p1 - q1;

    // ---- halo scalars via shuffles (all lanes active) ----
    // left: x[base-5..base-1] = prev thread's elements 3..7
    float Lu[5], Lv[5], Ru[5], Rv[5];
    Lu[0] = __shfl_up(u0.w, 1); Lv[0] = __shfl_up(v0.w, 1);
    Lu[1] = __shfl_up(u1.x, 1); Lv[1] = __shfl_up(v1.x, 1);
    Lu[2] = __shfl_up(u1.y, 1); Lv[2] = __shfl_up(v1.y, 1);
    Lu[3] = __shfl_up(u1.z, 1); Lv[3] = __shfl_up(v1.z, 1);
    Lu[4] = __shfl_up(u1.w, 1); Lv[4] = __shfl_up(v1.w, 1);
    // right: x[base+8..base+12] = next thread's elements 0..4
    Ru[0] = __shfl_down(u0.x, 1); Rv[0] = __shfl_down(v0.x, 1);
    Ru[1] = __shfl_down(u0.y, 1); Rv[1] = __shfl_down(v0.y, 1);
    Ru[2] = __shfl_down(u0.z, 1); Rv[2] = __shfl_down(v0.z, 1);
    Ru[3] = __shfl_down(u0.w, 1); Rv[3] = __shfl_down(v0.w, 1);
    Ru[4] = __shfl_down(u1.x, 1); Rv[4] = __shfl_down(v1.x, 1);

    const bool leftEdge  = (rp == 0);
    const bool rightEdge = (rp == T - OPT);

    // wave-edge lanes: shuffle source invalid -> patch from global
    if (lane == 0 && !leftEdge) {                 // x[base-8 .. base-1]
        const f32x4 a0 = reinterpret_cast<const f32x4*>(pred + base - 8)[0];
        const f32x4 a1 = reinterpret_cast<const f32x4*>(pred + base - 8)[1];
        const f32x4 b0 = reinterpret_cast<const f32x4*>(targ + base - 8)[0];
        const f32x4 b1 = reinterpret_cast<const f32x4*>(targ + base - 8)[1];
        Lu[0] = a0.w + b0.w; Lv[0] = a0.w - b0.w;
        Lu[1] = a1.x + b1.x; Lv[1] = a1.x - b1.x;
        Lu[2] = a1.y + b1.y; Lv[2] = a1.y - b1.y;
        Lu[3] = a1.z + b1.z; Lv[3] = a1.z - b1.z;
        Lu[4] = a1.w + b1.w; Lv[4] = a1.w - b1.w;
    }
    if (lane == 63 && !rightEdge) {               // x[base+8 .. base+15]
        const f32x4 c0 = reinterpret_cast<const f32x4*>(pred + base + 8)[0];
        const f32x4 c1 = reinterpret_cast<const f32x4*>(pred + base + 8)[1];
        const f32x4 d0 = reinterpret_cast<const f32x4*>(targ + base + 8)[0];
        const f32x4 d1 = reinterpret_cast<const f32x4*>(targ + base + 8)[1];
        Ru[0] = c0.x + d0.x; Rv[0] = c0.x - d0.x;
        Ru[1] = c0.y + d0.y; Rv[1] = c0.y - d0.y;
        Ru[2] = c0.z + d0.z; Rv[2] = c0.z - d0.z;
        Ru[3] = c0.w + d0.w; Rv[3] = c0.w - d0.w;
        Ru[4] = c1.x + d1.x; Rv[4] = c1.x - d1.x;
    }
    if (leftEdge) {
        #pragma unroll
        for (int j = 0; j < 5; j++) { Lu[j] = 0.f; Lv[j] = 0.f; }
    }
    if (rightEdge) {
        #pragma unroll
        for (int j = 0; j < 5; j++) { Ru[j] = 0.f; Rv[j] = 0.f; }
    }

    // ---- aligned window pairs A[c] = {x[base+2c-6], x[base+2c-5]}, c=0..9 ----
    // (A[0].x = x[base-6] and A[9].y = x[base+13] are never used by any tap)
    f32x2 AU[10], AV[10];
    AU[0] = {0.f,   Lu[0]}; AV[0] = {0.f,   Lv[0]};
    AU[1] = {Lu[1], Lu[2]}; AV[1] = {Lv[1], Lv[2]};
    AU[2] = {Lu[3], Lu[4]}; AV[2] = {Lv[3], Lv[4]};
    AU[3] = {u0.x,  u0.y};  AV[3] = {v0.x,  v0.y};
    AU[4] = {u0.z,  u0.w};  AV[4] = {v0.z,  v0.w};
    AU[5] = {u1.x,  u1.y};  AV[5] = {v1.x,  v1.y};
    AU[6] = {u1.z,  u1.w};  AV[6] = {v1.z,  v1.w};
    AU[7] = {Ru[0], Ru[1]}; AV[7] = {Rv[0], Rv[1]};
    AU[8] = {Ru[2], Ru[3]}; AV[8] = {Rv[2], Rv[3]};
    AU[9] = {Ru[4], 0.f};   AV[9] = {Rv[4], 0.f};

    // accumulators: acc[p] = {conv(out 2p), conv(out 2p+1)}
    f32x2 aU[4] = {}, aV[4] = {}, aUU[4] = {}, aVV[4] = {};

    // odd taps k: data pair for outputs (2p,2p+1) = A[p + (k+1)/2]  (even e)
    #pragma unroll
    for (int c = 1; c <= 8; c++) {                // c=0,9 have no odd-k taps
        f32x2 sU, sV;
        PK_SQ(sU, AU[c]); PK_SQ(sV, AV[c]);
        #pragma unroll
        for (int k = 1; k < 11; k += 2) {
            const int p = c - (k + 1) / 2;
            if (p < 0 || p > 3) continue;
            PK_FMA(aU[p],  AU[c], wts.w[k]);
            PK_FMA(aV[p],  AV[c], wts.w[k]);
            PK_FMA(aUU[p], sU,    wts.w[k]);
            PK_FMA(aVV[p], sV,    wts.w[k]);
        }
    }
    // even taps k: data pair = O[p + k/2] where O[d] = {A[d].y, A[d+1].x} (odd e)
    #pragma unroll
    for (int d = 0; d < 9; d++) {
        const f32x2 OU = {AU[d].y, AU[d + 1].x};
        const f32x2 OV = {AV[d].y, AV[d + 1].x};
        f32x2 sU, sV;
        PK_SQ(sU, OU); PK_SQ(sV, OV);
        #pragma unroll
        for (int k = 0; k < 11; k += 2) {
            const int p = d - k / 2;
            if (p < 0 || p > 3) continue;
            PK_FMA(aU[p],  OU, wts.w[k]);
            PK_FMA(aV[p],  OV, wts.w[k]);
            PK_FMA(aUU[p], sU, wts.w[k]);
            PK_FMA(aVV[p], sV, wts.w[k]);
        }
    }

    // ---- SSIM epilogue: acc halves are per-output conv values ----
    float qsum = 0.f;
    #pragma unroll
    for (int p = 0; p < 4; p++) {
        const f32x2 aa = aU[p] * aU[p], bb = aV[p] * aV[p];
        const f32x2 e   = 0.5f * (aa - bb);           // 2*mu1*mu2
        const f32x2 f2  = 0.5f * (aa + bb);           // mu1^2+mu2^2
        const f32x2 t2  = 0.5f * (aUU[p] - aVV[p]);   // 2*s12
        const f32x2 sP  = 0.5f * (aUU[p] + aVV[p]);   // s11+s22
        const f32x2 num = (e + C1f) * (t2 - e + C2f);
        const f32x2 den = (f2 + C1f) * (sP - f2 + C2f);
        qsum += num.x * __builtin_amdgcn_rcpf(den.x); // den >= C1*C2 > 0
        qsum += num.y * __builtin_amdgcn_rcpf(den.y);
    }

    // ---- block reduction -> one partial per block ----
    #pragma unroll
    for (int off = 32; off; off >>= 1) qsum += __shfl_down(qsum, off);
    __shared__ float wsum[TPB / 64];
    if ((threadIdx.x & 63) == 0) wsum[threadIdx.x >> 6] = qsum;
    __syncthreads();
    if (threadIdx.x == 0) {
        float s = 0.f;
        #pragma unroll
        for (int i = 0; i < TPB / 64; i++) s += wsum[i];
        partial[blockIdx.x] = s;
    }
}

__global__ __launch_bounds__(256) void ssim_reduce(
    const f32x4* __restrict__ partial4, int n4, float* __restrict__ out, float inv_n)
{
    float s = 0.f;
    for (int i = threadIdx.x; i < n4; i += 256) {
        const f32x4 p = partial4[i];
        s += (p.x + p.y) + (p.z + p.w);
    }
    #pragma unroll
    for (int off = 32; off; off >>= 1) s += __shfl_down(s, off);
    __shared__ float ws[4];
    if ((threadIdx.x & 63) == 0) ws[threadIdx.x >> 6] = s;
    __syncthreads();
    if (threadIdx.x == 0) {
        float t = 0.f;
        #pragma unroll
        for (int i = 0; i < 4; i++) t += ws[i];
        out[0] = 1.f - t * inv_n;                 // mean(1-ssim) = 1 - mean(ssim)
    }
}

extern "C" void kernel_launch(void* const* d_in, const int* in_sizes, int n_in,
                              void* d_out, int out_size, void* d_ws, size_t ws_size,
                              hipStream_t stream)
{
    const float* pred = (const float*)d_in[0];
    const float* targ = (const float*)d_in[1];
    float* out = (float*)d_out;
    float* partial = (float*)d_ws;

    const int n      = in_sizes[0];               // B*C*T = 24,576,000
    const int blocks = n / OPT / TPB;             // 12,000 exactly (48 KB d_ws)

    // Gaussian window on host in double (matches numpy), splat pairs.
    double g[11], s = 0.0;
    for (int i = 0; i < 11; i++) { g[i] = exp(-((i - 5) * (i - 5)) / 4.5); s += g[i]; }
    WS wts;
    for (int i = 0; i < 11; i++) {
        const float w = (float)(g[i] / s);
        wts.w[i].x = w; wts.w[i].y = w;
    }

    hipLaunchKernelGGL(ssim_main, dim3(blocks), dim3(TPB), 0, stream,
                       pred, targ, partial, wts);
    hipLaunchKernelGGL(ssim_reduce, dim3(1), dim3(256), 0, stream,
                       (const f32x4*)partial, blocks / 4, out, 1.0f / (float)n);
}